// Round 13
// baseline (573.810 us; speedup 1.0000x reference)
//
#include <hip/hip_runtime.h>

// ---------------- problem constants ----------------
#define B_      8
#define A_      64
#define NPAIR   63
#define NC_     128
#define NF_     2560    // K
#define O2_     196     // 14*14
#define NORB_   14
#define AO_     896
#define NCOLS   588     // computed cols: [H_off 196 | S_off 196 | H_on 196]
#define NSTORE  392     // cols stored to HSoff
#define CSTRIDE 400     // padded col stride of HSoff (1600 B)
#define KSTEPS  80      // NF_/32
#define BN      640
#define BSTEP_BYTES 40960   // BN*32*2 per K-step

typedef short bf16x8 __attribute__((ext_vector_type(8)));
typedef float f32x4  __attribute__((ext_vector_type(4)));

__device__ __forceinline__ unsigned f2bf(float f) {
    unsigned u = __builtin_bit_cast(unsigned, f);
    return (u + 0x7fffu + ((u >> 16) & 1u)) >> 16;   // RNE
}

// ---------------- kernel 1: fused {pack weights | energy head} ----------------
__global__ __launch_bounds__(512)
void prep_energy(const float* __restrict__ W_off, const float* __restrict__ W_ovoff,
                 const float* __restrict__ W_on, unsigned short* __restrict__ Bws,
                 const float* __restrict__ x, const float* __restrict__ W1,
                 const float* __restrict__ b1, const float* __restrict__ W2,
                 const float* __restrict__ b2, float* __restrict__ E) {
    const int t = threadIdx.x;
    if (blockIdx.x < KSTEPS) {
        __shared__ float wt[32 * BN];
        const int ks = blockIdx.x;
        for (int e = t; e < 32 * BN; e += 512) {
            int kl = e / BN, c = e - kl * BN;
            int kg = ks * 32 + kl;
            float v = 0.f;
            if (c < O2_)          v = W_off  [(size_t)kg * O2_ + c];
            else if (c < 2 * O2_) v = W_ovoff[(size_t)kg * O2_ + (c - O2_)];
            else if (c < 3 * O2_) v = W_on   [(size_t)kg * O2_ + (c - 2 * O2_)];
            wt[kl * BN + c] = v;
        }
        __syncthreads();
        unsigned short* out = Bws + (size_t)ks * (BN * 32);
        for (int e = t; e < BN * 4; e += 512) {
            int n = e >> 2, sg = e & 3;
            uint4 w;
            w.x = f2bf(wt[(sg * 8 + 0) * BN + n]) | (f2bf(wt[(sg * 8 + 1) * BN + n]) << 16);
            w.y = f2bf(wt[(sg * 8 + 2) * BN + n]) | (f2bf(wt[(sg * 8 + 3) * BN + n]) << 16);
            w.z = f2bf(wt[(sg * 8 + 4) * BN + n]) | (f2bf(wt[(sg * 8 + 5) * BN + n]) << 16);
            w.w = f2bf(wt[(sg * 8 + 6) * BN + n]) | (f2bf(wt[(sg * 8 + 7) * BN + n]) << 16);
            *(uint4*)(out + (size_t)n * 32 + sg * 8) = w;
        }
    } else {
        __shared__ float partial[8];
        const int b = blockIdx.x - KSTEPS;
        const int lane = t & 63;
        const int w = t >> 6;
        float esum = 0.f;
        for (int aa = 0; aa < 8; ++aa) {
            const int a = w * 8 + aa;
            const float* xr = x + (size_t)(b * A_ + a) * NC_;
            float hj = b1[lane];
            for (int k = 0; k < NC_; ++k) hj = fmaf(xr[k], W1[k * 64 + lane], hj);
            float sp = fmaxf(hj, 0.f) + log1pf(expf(-fabsf(hj))) - 0.69314718055994531f;
            float v = sp * W2[lane];
            for (int off = 32; off; off >>= 1) v += __shfl_down(v, off);
            if (lane == 0) esum += v + b2[0];
        }
        if (lane == 0) partial[w] = esum;
        __syncthreads();
        if (t == 0) {
            float e = 0.f;
            for (int k = 0; k < 8; ++k) e += partial[k];
            E[b] = e;
        }
    }
}

// ---------------- kernel 2: barrier-free MFMA GEMM + fused Hon ----------------
// 512 blocks = 1 atom (63 pair rows) each; 16 waves 2Mx8N, wave 32x80, acc[2][5].
// NO LDS, NO barriers in main loop: A fp32 -> regs (cvt_pk), B rolling 5-reg window.
// Waves self-schedule; L1 dedups the wm-twin A reads and wm-duplicate B reads.
__global__ __launch_bounds__(1024, 4)
void gemm_off(const float* __restrict__ V, const unsigned short* __restrict__ Bws,
              const float* __restrict__ b_off, const float* __restrict__ b_ovoff,
              const float* __restrict__ b_on, float* __restrict__ HSoff,
              float* __restrict__ Hon) {
    __shared__ float HonLds[O2_];              // epilogue only

    const int tid  = threadIdx.x;
    int mtb = blockIdx.x;
    mtb = (mtb & 7) * 64 + (mtb >> 3);         // XCD swizzle: 512 = 8 x 64 bijective
    const int mt   = mtb;                      // atom index 0..511
    const int lane = tid & 63;
    const int wv   = tid >> 6;                 // 0..15
    const int wm   = wv >> 3, wn = wv & 7;     // 2M x 8N, wave tile 32x80

    // A: lane (r = lane&15, q = lane>>4) reads V[mt*63 + wm*32 + mf*16 + r][t*32 + q*8 .. +7]
    const int r0 = wm * 32 + (lane & 15);
    const int rowA0 = mt * NPAIR + (r0      < NPAIR ? r0      : NPAIR - 1);
    const int rowA1 = mt * NPAIR + (r0 + 16 < NPAIR ? r0 + 16 : NPAIR - 1);
    const float* ap0 = V + (size_t)rowA0 * NF_ + (lane >> 4) * 8;
    const float* ap1 = V + (size_t)rowA1 * NF_ + (lane >> 4) * 8;

    // B fragment base: frag(t,nf) at n = wn*80 + nf*16 + (lane&15), k-quarter (lane>>4)
    const char* bp = (const char*)Bws + (size_t)(wn * 80 + (lane & 15)) * 64 + (lane >> 4) * 16;
#define BFRAG(t_, nf_) (*(const bf16x8*)(bp + (size_t)(t_) * BSTEP_BYTES + (nf_) * 1024))

    f32x4 acc[2][5];
#pragma unroll
    for (int mf = 0; mf < 2; ++mf)
#pragma unroll
        for (int nf = 0; nf < 5; ++nf)
            acc[mf][nf] = (f32x4){0.f, 0.f, 0.f, 0.f};

    union U8 { unsigned u[4]; bf16x8 v; };
#define CVT8(dst_, lo_, hi_) {                                                      \
    U8 uu_;                                                                         \
    asm("v_cvt_pk_bf16_f32 %0, %1, %2" : "=v"(uu_.u[0]) : "v"(lo_.x), "v"(lo_.y));  \
    asm("v_cvt_pk_bf16_f32 %0, %1, %2" : "=v"(uu_.u[1]) : "v"(lo_.z), "v"(lo_.w));  \
    asm("v_cvt_pk_bf16_f32 %0, %1, %2" : "=v"(uu_.u[2]) : "v"(hi_.x), "v"(hi_.y));  \
    asm("v_cvt_pk_bf16_f32 %0, %1, %2" : "=v"(uu_.u[3]) : "v"(hi_.z), "v"(hi_.w));  \
    dst_ = uu_.v; }

#define MFMA1(abf_, bq_, mf_, nf_) \
    acc[mf_][nf_] = __builtin_amdgcn_mfma_f32_16x16x32_bf16(abf_, bq_, acc[mf_][nf_], 0, 0, 0);

    bf16x8 bq0, bq1, bq2, bq3, bq4, af0, af1;
    float4 p0l, p0h, p1l, p1h;

    // ---- prologue: A(0) + B(0) ----
    p0l = ((const float4*)(ap0))[0]; p0h = ((const float4*)(ap0))[1];
    p1l = ((const float4*)(ap1))[0]; p1h = ((const float4*)(ap1))[1];
    bq0 = BFRAG(0, 0); bq1 = BFRAG(0, 1); bq2 = BFRAG(0, 2); bq3 = BFRAG(0, 3); bq4 = BFRAG(0, 4);
    CVT8(af0, p0l, p0h);
    CVT8(af1, p1l, p1h);

    for (int t = 0; t < KSTEPS; ++t) {
        const int tn = (t + 1 < KSTEPS) ? t + 1 : KSTEPS - 1;   // clamped (tail redundancy)
        // issue A(t+1) at step top: full-step HBM latency cover
        const float* a0n = ap0 + (size_t)tn * 32;
        const float* a1n = ap1 + (size_t)tn * 32;
        p0l = ((const float4*)a0n)[0]; p0h = ((const float4*)a0n)[1];
        p1l = ((const float4*)a1n)[0]; p1h = ((const float4*)a1n)[1];

        // MFMA on af(t) x bq(t); bq(t+1) reloads at last use (WAR pins order)
        MFMA1(af0, bq0, 0, 0);
        MFMA1(af0, bq1, 0, 1);
        MFMA1(af0, bq2, 0, 2);
        MFMA1(af0, bq3, 0, 3);
        MFMA1(af0, bq4, 0, 4);
        MFMA1(af1, bq0, 1, 0); bq0 = BFRAG(tn, 0);
        MFMA1(af1, bq1, 1, 1); bq1 = BFRAG(tn, 1);
        MFMA1(af1, bq2, 1, 2); bq2 = BFRAG(tn, 2);
        MFMA1(af1, bq3, 1, 3); bq3 = BFRAG(tn, 3);
        MFMA1(af1, bq4, 1, 4); bq4 = BFRAG(tn, 4);

        // convert A(t+1) (waits on the step-top loads; af WAR after last MFMA use)
        CVT8(af0, p0l, p0h);
        CVT8(af1, p1l, p1h);
    }

    // ---- epilogue ----
    if (tid < O2_) HonLds[tid] = 0.f;
    __syncthreads();

    const int c16 = lane & 15, rg = lane >> 4;
    // off-site cols -> HSoff (+bias)
#pragma unroll
    for (int nf = 0; nf < 5; ++nf) {
        const int C = wn * 80 + nf * 16 + c16;
        if (C >= NSTORE) continue;
        const float bias = (C < O2_) ? b_off[C] : b_ovoff[C - O2_];
#pragma unroll
        for (int mf = 0; mf < 2; ++mf) {
            const int L = wm * 32 + mf * 16 + rg * 4;
#pragma unroll
            for (int jj = 0; jj < 4; ++jj) {
                const int row = L + jj;
                if (row < NPAIR)
                    HSoff[(size_t)(mt * NPAIR + row) * CSTRIDE + C] = acc[mf][nf][jj] + bias;
            }
        }
    }
    // on-site cols -> in-block mean reduction
#pragma unroll
    for (int nf = 0; nf < 5; ++nf) {
        const int C = wn * 80 + nf * 16 + c16;
        if (C < NSTORE || C >= NCOLS) continue;
        const int cc = C - NSTORE;
        float s = 0.f;
#pragma unroll
        for (int mf = 0; mf < 2; ++mf) {
            const int L = wm * 32 + mf * 16 + rg * 4;
#pragma unroll
            for (int jj = 0; jj < 4; ++jj)
                if (L + jj < NPAIR) s += acc[mf][nf][jj];
        }
        s += __shfl_down(s, 32);
        s += __shfl_down(s, 16);
        if (lane < 16) atomicAdd(&HonLds[cc], s);
    }
    __syncthreads();
    if (tid < O2_)
        Hon[(size_t)mt * O2_ + tid] = HonLds[tid] * (1.f / (float)NPAIR) + b_on[tid];
#undef BFRAG
#undef CVT8
#undef MFMA1
}

// ---------------- kernel 3: assemble H and S, LDS-staged, fully coalesced ----------------
__global__ __launch_bounds__(256)
void assemble_k(const float* __restrict__ HSoff, const float* __restrict__ Hon,
                const int* __restrict__ Z, const float* __restrict__ ov_emb,
                const float* __restrict__ orbE, const float* __restrict__ s0E,
                float* __restrict__ H, float* __restrict__ S) {
    __shared__ float Ai[NPAIR * 197];
    __shared__ float Bj[2][16 * 200];
    __shared__ float Dg[O2_];
    __shared__ float Dd[NORB_];

    const int bid = blockIdx.x;
    const int h = bid & 1, i = (bid >> 1) & 63, b = bid >> 7;
    const int t = threadIdx.x;
    const int g = b * A_ + i;
    const int z = Z[g];
    float* out = (h ? S : H) + (size_t)b * AO_ * AO_;

    const float* abase = HSoff + (size_t)g * NPAIR * CSTRIDE + h * O2_;
    for (int u = t; u < NPAIR * O2_; u += 256) {
        int jj = u / O2_, e = u - jj * O2_;
        Ai[jj * 197 + e] = abase[(size_t)jj * CSTRIDE + e];
    }
    if (t < O2_)   Dg[t] = h ? ov_emb[(size_t)z * O2_ + t]   : Hon[(size_t)g * O2_ + t];
    if (t < NORB_) Dd[t] = h ? s0E[(size_t)z * NORB_ + t]    : orbE[(size_t)z * NORB_ + t];

    auto stageB = [&](int buf, int jc) {
        for (int u = t; u < 16 * O2_; u += 256) {
            int jl = u / O2_, e = u - jl * O2_;
            int j = jc * 16 + jl;
            if (j != i) {
                int idx = (i < j) ? i : i - 1;
                Bj[buf][jl * 200 + e] =
                    HSoff[((size_t)(b * A_ + j) * NPAIR + idx) * CSTRIDE + h * O2_ + e];
            }
        }
    };
    stageB(0, 0);
    __syncthreads();

    const int tj = t / NORB_, tq = t - tj * NORB_;   // valid for t<224
    for (int jc = 0; jc < 4; ++jc) {
        if (jc < 3) stageB((jc + 1) & 1, jc + 1);
        if (t < 224) {
            const int j = jc * 16 + tj;
            const int cur = jc & 1;
#pragma unroll
            for (int p = 0; p < NORB_; ++p) {
                float v;
                if (j == i) {
                    v = 0.5f * (Dg[p * NORB_ + tq] + Dg[tq * NORB_ + p]);
                    if (p == tq) v += Dd[p];
                } else {
                    int jj = (j < i) ? j : j - 1;
                    v = 0.5f * (Ai[jj * 197 + p * NORB_ + tq] + Bj[cur][tj * 200 + tq * NORB_ + p]);
                }
                out[(size_t)(i * NORB_ + p) * AO_ + jc * 224 + t] = v;
            }
        }
        __syncthreads();
    }
}

// ---------------- launcher ----------------
extern "C" void kernel_launch(void* const* d_in, const int* in_sizes, int n_in,
                              void* d_out, int out_size, void* d_ws, size_t ws_size,
                              hipStream_t stream) {
    const int*   Z       = (const int*)  d_in[0];
    const float* x       = (const float*)d_in[2];
    const float* V       = (const float*)d_in[3];
    const float* W_off   = (const float*)d_in[4];
    const float* b_off   = (const float*)d_in[5];
    const float* W_on    = (const float*)d_in[6];
    const float* b_on    = (const float*)d_in[7];
    const float* W_ovoff = (const float*)d_in[8];
    const float* b_ovoff = (const float*)d_in[9];
    const float* ov_emb  = (const float*)d_in[10];
    const float* orbE    = (const float*)d_in[11];
    const float* s0E     = (const float*)d_in[12];
    const float* W1      = (const float*)d_in[13];
    const float* b1      = (const float*)d_in[14];
    const float* W2      = (const float*)d_in[15];
    const float* b2      = (const float*)d_in[16];

    float* H = (float*)d_out;
    float* S = H + (size_t)B_ * AO_ * AO_;
    float* E = S + (size_t)B_ * AO_ * AO_;

    char* ws = (char*)d_ws;
    unsigned short* Bws = (unsigned short*)ws;                     // 81 steps x 40960 B (step 80 = pad)
    float* HSoff = (float*)(ws + (size_t)4  * 1024 * 1024);        // 32256*400*4 = 51,609,600 B
    float* Hon   = (float*)(ws + (size_t)60 * 1024 * 1024);        //    401,408 B

    prep_energy<<<KSTEPS + B_, 512, 0, stream>>>(W_off, W_ovoff, W_on, Bws,
                                                 x, W1, b1, W2, b2, E);
    gemm_off   <<<512,  1024, 0, stream>>>(V, Bws, b_off, b_ovoff, b_on, HSoff, Hon);
    assemble_k <<<1024, 256,  0, stream>>>(HSoff, Hon, Z, ov_emb, orbE, s0E, H, S);
}

// Round 14
// 288.160 us; speedup vs baseline: 1.9913x; 1.9913x over previous
//
#include <hip/hip_runtime.h>

// ---------------- problem constants ----------------
#define B_      8
#define A_      64
#define NPAIR   63
#define NC_     128
#define NF_     2560    // K
#define O2_     196     // 14*14
#define NORB_   14
#define AO_     896
#define NCOLS   588     // computed cols: [H_off 196 | S_off 196 | H_on 196]
#define NSTORE  392     // cols stored to HSoff
#define CSTRIDE 400     // padded col stride of HSoff
#define KSTEPS  80      // K32 slices
#define NMACRO  20      // K128 macro-steps
#define BM      126     // 2 atoms x 63 pair-rows per block
#define BN      640
#define MAC_BYTES 81920 // 640 cols x 128 k-bytes per macro

typedef float f32x4 __attribute__((ext_vector_type(4)));
typedef int   v8i   __attribute__((ext_vector_type(8)));
typedef int   v4i   __attribute__((ext_vector_type(4)));

#define SCA 0x7F7F7F7F   // A scale bytes: e8m0 127 = 1.0
#define SCB 0x7C7C7C7C   // B scale bytes: e8m0 124 = 2^-3 (W packed x8)

__device__ __forceinline__ unsigned f2bf(float f) {
    unsigned u = __builtin_bit_cast(unsigned, f);
    return (u + 0x7fffu + ((u >> 16) & 1u)) >> 16;
}

// ---------------- kernel 1: fused {pack W -> fp8 frag layout | energy head} ----------------
// Bws: [21 macros][640 n][128 k] fp8 e4m3, W scaled x8 (dequant via MFMA scale 2^-3).
__global__ __launch_bounds__(512)
void prep_energy(const float* __restrict__ W_off, const float* __restrict__ W_ovoff,
                 const float* __restrict__ W_on, unsigned char* __restrict__ Bws,
                 const float* __restrict__ x, const float* __restrict__ W1,
                 const float* __restrict__ b1, const float* __restrict__ W2,
                 const float* __restrict__ b2, float* __restrict__ E) {
    const int t = threadIdx.x;
    if (blockIdx.x < KSTEPS) {
        __shared__ float wt[32 * BN];
        const int ks = blockIdx.x;
        for (int e = t; e < 32 * BN; e += 512) {
            int kl = e / BN, c = e - kl * BN;
            int kg = ks * 32 + kl;
            float v = 0.f;
            if (c < O2_)          v = W_off  [(size_t)kg * O2_ + c];
            else if (c < 2 * O2_) v = W_ovoff[(size_t)kg * O2_ + (c - O2_)];
            else if (c < 3 * O2_) v = W_on   [(size_t)kg * O2_ + (c - 2 * O2_)];
            wt[kl * BN + c] = v * 8.0f;
        }
        __syncthreads();
        unsigned char* out = Bws + (size_t)(ks >> 2) * MAC_BYTES + (ks & 3) * 32;
        for (int u = t; u < BN * 8; u += 512) {
            int n = u >> 3, q = u & 7;
            int w = __builtin_amdgcn_cvt_pk_fp8_f32(wt[(q*4+0)*BN+n], wt[(q*4+1)*BN+n], 0, false);
            w     = __builtin_amdgcn_cvt_pk_fp8_f32(wt[(q*4+2)*BN+n], wt[(q*4+3)*BN+n], w, true);
            *(int*)(out + (size_t)n * 128 + q * 4) = w;
        }
    } else {
        __shared__ float partial[8];
        const int b = blockIdx.x - KSTEPS;
        const int lane = t & 63;
        const int w = t >> 6;
        float esum = 0.f;
        for (int aa = 0; aa < 8; ++aa) {
            const int a = w * 8 + aa;
            const float* xr = x + (size_t)(b * A_ + a) * NC_;
            float hj = b1[lane];
            for (int k = 0; k < NC_; ++k) hj = fmaf(xr[k], W1[k * 64 + lane], hj);
            float sp = fmaxf(hj, 0.f) + log1pf(expf(-fabsf(hj))) - 0.69314718055994531f;
            float v = sp * W2[lane];
            for (int off = 32; off; off >>= 1) v += __shfl_down(v, off);
            if (lane == 0) esum += v + b2[0];
        }
        if (lane == 0) partial[w] = esum;
        __syncthreads();
        if (t == 0) {
            float e = 0.f;
            for (int k = 0; k < 8; ++k) e += partial[k];
            E[b] = e;
        }
    }
}

// ---------------- kernel 2: fp8 MX-scale MFMA GEMM + fused Hon ----------------
// BM=126, 256 blocks (1/CU), 8 waves 2Mx4N, acc[4][10], K128 macro-steps.
// A: fp32 gload_lds 8-slot K32 ring -> conv phase -> single fp8 tile [4 sub][128r][48B].
// B: fp8 frags from L2, 5-reg rolling window (reload after last use).
__global__ __launch_bounds__(512, 2)
void gemm_off(const float* __restrict__ V, const unsigned char* __restrict__ Bws,
              const float* __restrict__ b_off, const float* __restrict__ b_ovoff,
              const float* __restrict__ b_on, float* __restrict__ HSoff,
              float* __restrict__ Hon) {
    __shared__ alignas(16) float Af32[8][4096];           // 128 KB ring (K32 slices, 128 rows x 128B)
    __shared__ alignas(16) unsigned char Afp8[4 * 6144];  // 24 KB: [sub][128 rows][48B (32 used)]
    __shared__ float HonLds[2][O2_];

    const int tid  = threadIdx.x;
    const int mt   = blockIdx.x;
    const int lane = tid & 63;
    const int wv   = tid >> 6;
    const int wm   = wv >> 2, wn = wv & 3;     // 2M x 4N, wave tile 64x160
    const int wvu  = __builtin_amdgcn_readfirstlane(wv);

    // A staging: chunk tid (rows 0..63) and tid+512 (rows 64..127, clamped src)
    const int r0  = tid >> 3;
    const int r1c = (64 + r0) > 125 ? 125 : (64 + r0);
    const int sg  = tid & 7;
    const float* asrc0 = V + (size_t)(mt * BM + r0)  * NF_ + sg * 4;
    const float* asrc1 = V + (size_t)(mt * BM + r1c) * NF_ + sg * 4;

    // B frag base: frag(T,nf) lane (c=lane&15, q=lane>>4): 32B at ((T*640 + wn*160+nf*16+c)*128 + q*32)
    const unsigned char* bbase = Bws + ((size_t)(wn * 160 + (lane & 15))) * 128 + (lane >> 4) * 32;
#define BLD(T_, nf_) (*(const v8i*)(bbase + (size_t)(T_) * MAC_BYTES + (nf_) * 2048))

    // A frag base: lane (r=lane&15, q=lane>>4): sub q, row wm*64 + r (+ mf*16), 32B
    const unsigned aoff = (unsigned)(lane >> 4) * 6144 + (unsigned)(wm * 64 + (lane & 15)) * 48;

    f32x4 acc[4][10];
#pragma unroll
    for (int mf = 0; mf < 4; ++mf)
#pragma unroll
        for (int nf = 0; nf < 10; ++nf)
            acc[mf][nf] = (f32x4){0.f, 0.f, 0.f, 0.f};

    auto stage = [&](int slot, int k32) {
        __builtin_amdgcn_global_load_lds(
            (const __attribute__((address_space(1))) void*)(asrc0 + (size_t)k32 * 32),
            (__attribute__((address_space(3))) void*)(&Af32[slot][wvu * 256]), 16, 0, 0);
        __builtin_amdgcn_global_load_lds(
            (const __attribute__((address_space(1))) void*)(asrc1 + (size_t)k32 * 32),
            (__attribute__((address_space(3))) void*)(&Af32[slot][2048 + wvu * 256]), 16, 0, 0);
    };
    auto conv = [&](int slot, int sub) {
        const char* sp = (const char*)&Af32[slot][0];
        float4 f0 = *(const float4*)(sp + tid * 16);
        float4 f1 = *(const float4*)(sp + tid * 16 + 8192);
        int w0 = __builtin_amdgcn_cvt_pk_fp8_f32(f0.x, f0.y, 0, false);
        w0     = __builtin_amdgcn_cvt_pk_fp8_f32(f0.z, f0.w, w0, true);
        int w1 = __builtin_amdgcn_cvt_pk_fp8_f32(f1.x, f1.y, 0, false);
        w1     = __builtin_amdgcn_cvt_pk_fp8_f32(f1.z, f1.w, w1, true);
        *(int*)&Afp8[sub * 6144 + (tid >> 3) * 48 + (tid & 7) * 4] = w0;
        *(int*)&Afp8[sub * 6144 + (64 + (tid >> 3)) * 48 + (tid & 7) * 4] = w1;
    };

    union AV { v4i h[2]; v8i v; };
#define AFLD(dst_, mf_) { AV a_; \
    a_.h[0] = *(const v4i*)&Afp8[aoff + (mf_) * 768];      \
    a_.h[1] = *(const v4i*)&Afp8[aoff + (mf_) * 768 + 16]; \
    dst_ = a_.v; }

#define MFMA1(abf_, bq_, mf_, nf_) \
    acc[mf_][nf_] = __builtin_amdgcn_mfma_scale_f32_16x16x128_f8f6f4( \
        abf_, bq_, acc[mf_][nf_], 0, 0, 0, SCA, 0, SCB);

#define C4(bv_, nf_) { \
    __builtin_amdgcn_s_setprio(1); \
    MFMA1(af0, bv_, 0, nf_); MFMA1(af1, bv_, 1, nf_); \
    MFMA1(af2, bv_, 2, nf_); MFMA1(af3, bv_, 3, nf_); \
    __builtin_amdgcn_s_setprio(0); }

    v8i b0, b1, b2, b3, b4, af0, af1, af2, af3;

    // ---- prologue: stage macro0 subs (slots 0..3); preload B window F(0..4) ----
    stage(0, 0); stage(1, 1); stage(2, 2); stage(3, 3);
    b0 = BLD(0, 0); b1 = BLD(0, 1); b2 = BLD(0, 2); b3 = BLD(0, 3); b4 = BLD(0, 4);

    for (int T = 0; T < NMACRO; ++T) {
        const int sb = (T & 1) * 4;            // slots holding macro T subs
        const int st = ((T + 1) & 1) * 4;      // dest slots for macro T+1 subs
#pragma unroll
        for (int i = 0; i < 4; ++i) {
            // guarantee stage(T, sub i) retired; keep 10 bq ops + newer stages in flight
            asm volatile("s_waitcnt vmcnt(16)" ::: "memory");
            __builtin_amdgcn_sched_barrier(0);
            if (T < NMACRO - 1) stage(st + i, 4 * (T + 1) + i);
            else                stage(st + i, 76 + i);   // tail dummy (slots hold conv'd macro-18 data)
            conv(sb + i, i);
        }
        asm volatile("s_waitcnt lgkmcnt(0)" ::: "memory");
        __builtin_amdgcn_sched_barrier(0);
        __builtin_amdgcn_s_barrier();
        __builtin_amdgcn_sched_barrier(0);

        // MFMA phase: af frags, 10 nf clusters, B reload-after-use (5-slot, period-10 invariant)
        AFLD(af0, 0); AFLD(af1, 1); AFLD(af2, 2); AFLD(af3, 3);
        C4(b0, 0); b0 = BLD(T, 5);
        C4(b1, 1); b1 = BLD(T, 6);
        C4(b2, 2); b2 = BLD(T, 7);
        C4(b3, 3); b3 = BLD(T, 8);
        C4(b4, 4); b4 = BLD(T, 9);
        C4(b0, 5); b0 = BLD(T + 1, 0);         // T=19 reads pad macro 20 (allocated, unused)
        C4(b1, 6); b1 = BLD(T + 1, 1);
        C4(b2, 7); b2 = BLD(T + 1, 2);
        C4(b3, 8); b3 = BLD(T + 1, 3);
        C4(b4, 9); b4 = BLD(T + 1, 4);
        __builtin_amdgcn_sched_barrier(0);
        __builtin_amdgcn_s_barrier();
        __builtin_amdgcn_sched_barrier(0);
    }

    // ---- epilogue: off-site -> HSoff (+bias); on-site -> block mean -> Hon ----
    if (tid < 2 * O2_) HonLds[tid / O2_][tid % O2_] = 0.f;
    __syncthreads();

    const int c16 = lane & 15, rg = lane >> 4;
#pragma unroll
    for (int nf = 0; nf < 10; ++nf) {
        const int C = wn * 160 + nf * 16 + c16;
        if (C >= NSTORE) continue;
        const float bias = (C < O2_) ? b_off[C] : b_ovoff[C - O2_];
#pragma unroll
        for (int mf = 0; mf < 4; ++mf) {
            const int L = wm * 64 + mf * 16 + rg * 4;
#pragma unroll
            for (int jj = 0; jj < 4; ++jj) {
                const int row = L + jj;
                if (row < BM)
                    HSoff[(size_t)(mt * BM + row) * CSTRIDE + C] = acc[mf][nf][jj] + bias;
            }
        }
    }
#pragma unroll
    for (int nf = 0; nf < 10; ++nf) {
        const int C = wn * 160 + nf * 16 + c16;
        if (C < NSTORE || C >= NCOLS) continue;
        const int cc = C - NSTORE;
        float s0 = 0.f, s1 = 0.f;
#pragma unroll
        for (int mf = 0; mf < 4; ++mf) {
            const int L = wm * 64 + mf * 16 + rg * 4;
#pragma unroll
            for (int jj = 0; jj < 4; ++jj) {
                const int row = L + jj;
                const float v = acc[mf][nf][jj];
                if (row < NPAIR)       s0 += v;
                else if (row < BM)     s1 += v;
            }
        }
        s0 += __shfl_down(s0, 32); s0 += __shfl_down(s0, 16);
        s1 += __shfl_down(s1, 32); s1 += __shfl_down(s1, 16);
        if (lane < 16) {
            atomicAdd(&HonLds[0][cc], s0);
            atomicAdd(&HonLds[1][cc], s1);
        }
    }
    __syncthreads();
    if (tid < 2 * O2_) {
        const int atom = tid / O2_, c = tid % O2_;
        Hon[(size_t)(mt * 2 + atom) * O2_ + c] =
            HonLds[atom][c] * (1.f / (float)NPAIR) + b_on[c];
    }
#undef BLD
#undef AFLD
#undef MFMA1
#undef C4
}

// ---------------- kernel 3: assemble H and S, LDS-staged, fully coalesced ----------------
__global__ __launch_bounds__(256)
void assemble_k(const float* __restrict__ HSoff, const float* __restrict__ Hon,
                const int* __restrict__ Z, const float* __restrict__ ov_emb,
                const float* __restrict__ orbE, const float* __restrict__ s0E,
                float* __restrict__ H, float* __restrict__ S) {
    __shared__ float Ai[NPAIR * 197];
    __shared__ float Bj[2][16 * 200];
    __shared__ float Dg[O2_];
    __shared__ float Dd[NORB_];

    const int bid = blockIdx.x;
    const int h = bid & 1, i = (bid >> 1) & 63, b = bid >> 7;
    const int t = threadIdx.x;
    const int g = b * A_ + i;
    const int z = Z[g];
    float* out = (h ? S : H) + (size_t)b * AO_ * AO_;

    const float* abase = HSoff + (size_t)g * NPAIR * CSTRIDE + h * O2_;
    for (int u = t; u < NPAIR * O2_; u += 256) {
        int jj = u / O2_, e = u - jj * O2_;
        Ai[jj * 197 + e] = abase[(size_t)jj * CSTRIDE + e];
    }
    if (t < O2_)   Dg[t] = h ? ov_emb[(size_t)z * O2_ + t]   : Hon[(size_t)g * O2_ + t];
    if (t < NORB_) Dd[t] = h ? s0E[(size_t)z * NORB_ + t]    : orbE[(size_t)z * NORB_ + t];

    auto stageB = [&](int buf, int jc) {
        for (int u = t; u < 16 * O2_; u += 256) {
            int jl = u / O2_, e = u - jl * O2_;
            int j = jc * 16 + jl;
            if (j != i) {
                int idx = (i < j) ? i : i - 1;
                Bj[buf][jl * 200 + e] =
                    HSoff[((size_t)(b * A_ + j) * NPAIR + idx) * CSTRIDE + h * O2_ + e];
            }
        }
    };
    stageB(0, 0);
    __syncthreads();

    const int tj = t / NORB_, tq = t - tj * NORB_;
    for (int jc = 0; jc < 4; ++jc) {
        if (jc < 3) stageB((jc + 1) & 1, jc + 1);
        if (t < 224) {
            const int j = jc * 16 + tj;
            const int cur = jc & 1;
#pragma unroll
            for (int p = 0; p < NORB_; ++p) {
                float v;
                if (j == i) {
                    v = 0.5f * (Dg[p * NORB_ + tq] + Dg[tq * NORB_ + p]);
                    if (p == tq) v += Dd[p];
                } else {
                    int jj = (j < i) ? j : j - 1;
                    v = 0.5f * (Ai[jj * 197 + p * NORB_ + tq] + Bj[cur][tj * 200 + tq * NORB_ + p]);
                }
                out[(size_t)(i * NORB_ + p) * AO_ + jc * 224 + t] = v;
            }
        }
        __syncthreads();
    }
}

// ---------------- launcher ----------------
extern "C" void kernel_launch(void* const* d_in, const int* in_sizes, int n_in,
                              void* d_out, int out_size, void* d_ws, size_t ws_size,
                              hipStream_t stream) {
    const int*   Z       = (const int*)  d_in[0];
    const float* x       = (const float*)d_in[2];
    const float* V       = (const float*)d_in[3];
    const float* W_off   = (const float*)d_in[4];
    const float* b_off   = (const float*)d_in[5];
    const float* W_on    = (const float*)d_in[6];
    const float* b_on    = (const float*)d_in[7];
    const float* W_ovoff = (const float*)d_in[8];
    const float* b_ovoff = (const float*)d_in[9];
    const float* ov_emb  = (const float*)d_in[10];
    const float* orbE    = (const float*)d_in[11];
    const float* s0E     = (const float*)d_in[12];
    const float* W1      = (const float*)d_in[13];
    const float* b1      = (const float*)d_in[14];
    const float* W2      = (const float*)d_in[15];
    const float* b2      = (const float*)d_in[16];

    float* H = (float*)d_out;
    float* S = H + (size_t)B_ * AO_ * AO_;
    float* E = S + (size_t)B_ * AO_ * AO_;

    char* ws = (char*)d_ws;
    unsigned char* Bws = (unsigned char*)ws;                       // 21 x 81920 = 1,720,320 B (macro 20 = pad)
    float* HSoff = (float*)(ws + (size_t)4  * 1024 * 1024);        // 32256*400*4 = 51,609,600 B
    float* Hon   = (float*)(ws + (size_t)60 * 1024 * 1024);        //    401,408 B

    prep_energy<<<KSTEPS + B_, 512, 0, stream>>>(W_off, W_ovoff, W_on, Bws,
                                                 x, W1, b1, W2, b2, E);
    gemm_off   <<<256,  512, 0, stream>>>(V, Bws, b_off, b_ovoff, b_on, HSoff, Hon);
    assemble_k <<<1024, 256, 0, stream>>>(HSoff, Hon, Z, ov_emb, orbE, s0E, H, S);
}

// Round 15
// 271.306 us; speedup vs baseline: 2.1150x; 1.0621x over previous
//
#include <hip/hip_runtime.h>

// ---------------- problem constants ----------------
#define B_      8
#define A_      64
#define NPAIR   63
#define NC_     128
#define NF_     2560    // K
#define O2_     196     // 14*14
#define NORB_   14
#define AO_     896
#define NCOLS   588     // computed cols: [H_off 196 | S_off 196 | H_on 196]
#define NSTORE  392     // cols stored to HSoff
#define CSTRIDE 400     // padded col stride of HSoff
#define KSTEPS  80      // K32 slices
#define NMACRO  20      // K128 macro-steps
#define BM      126     // 2 atoms x 63 pair-rows per block
#define BN      640
#define MAC_BYTES 81920 // B: 640 cols x 128 k-bytes per macro
#define ATILE   16384   // A: 128 rows x 128 k-bytes per (mtile, macro)

typedef float f32x4 __attribute__((ext_vector_type(4)));
typedef int   v8i   __attribute__((ext_vector_type(8)));

#define SCA 0x7F7F7F7F   // A scale: e8m0 127 = 1.0 (validated R14)
#define SCB 0x7C7C7C7C   // B scale: e8m0 124 = 2^-3 (W packed x8, validated R14)

__device__ __forceinline__ unsigned f2bf(float f) {
    unsigned u = __builtin_bit_cast(unsigned, f);
    return (u + 0x7fffu + ((u >> 16) & 1u)) >> 16;
}

// ---------------- kernel 1: fused {pack W -> fp8 | energy | V -> fp8 tiled} ----------------
// blocks 0..79: Bws pack; 80..87: energy; 88+: conv V -> Aws [mtile][T][row 0..125][k 128] fp8.
__global__ __launch_bounds__(512)
void prep_all(const float* __restrict__ W_off, const float* __restrict__ W_ovoff,
              const float* __restrict__ W_on, unsigned char* __restrict__ Bws,
              const float* __restrict__ x, const float* __restrict__ W1,
              const float* __restrict__ b1, const float* __restrict__ W2,
              const float* __restrict__ b2, float* __restrict__ E,
              const float* __restrict__ V, unsigned char* __restrict__ Aws) {
    const int t = threadIdx.x;
    if (blockIdx.x < KSTEPS) {
        __shared__ float wt[32 * BN];
        const int ks = blockIdx.x;
        for (int e = t; e < 32 * BN; e += 512) {
            int kl = e / BN, c = e - kl * BN;
            int kg = ks * 32 + kl;
            float v = 0.f;
            if (c < O2_)          v = W_off  [(size_t)kg * O2_ + c];
            else if (c < 2 * O2_) v = W_ovoff[(size_t)kg * O2_ + (c - O2_)];
            else if (c < 3 * O2_) v = W_on   [(size_t)kg * O2_ + (c - 2 * O2_)];
            wt[kl * BN + c] = v * 8.0f;
        }
        __syncthreads();
        unsigned char* out = Bws + (size_t)(ks >> 2) * MAC_BYTES + (ks & 3) * 32;
        for (int u = t; u < BN * 8; u += 512) {
            int n = u >> 3, q = u & 7;
            int w = __builtin_amdgcn_cvt_pk_fp8_f32(wt[(q*4+0)*BN+n], wt[(q*4+1)*BN+n], 0, false);
            w     = __builtin_amdgcn_cvt_pk_fp8_f32(wt[(q*4+2)*BN+n], wt[(q*4+3)*BN+n], w, true);
            *(int*)(out + (size_t)n * 128 + q * 4) = w;
        }
    } else if (blockIdx.x < KSTEPS + B_) {
        __shared__ float partial[8];
        const int b = blockIdx.x - KSTEPS;
        const int lane = t & 63;
        const int w = t >> 6;
        float esum = 0.f;
        for (int aa = 0; aa < 8; ++aa) {
            const int a = w * 8 + aa;
            const float* xr = x + (size_t)(b * A_ + a) * NC_;
            float hj = b1[lane];
            for (int k = 0; k < NC_; ++k) hj = fmaf(xr[k], W1[k * 64 + lane], hj);
            float sp = fmaxf(hj, 0.f) + log1pf(expf(-fabsf(hj))) - 0.69314718055994531f;
            float v = sp * W2[lane];
            for (int off = 32; off; off >>= 1) v += __shfl_down(v, off);
            if (lane == 0) esum += v + b2[0];
        }
        if (lane == 0) partial[w] = esum;
        __syncthreads();
        if (t == 0) {
            float e = 0.f;
            for (int k = 0; k < 8; ++k) e += partial[k];
            E[b] = e;
        }
    } else {
        // conv V: unit u = 16 k-floats of one row -> 16 fp8 bytes. 32256*160 units.
        const int u = (blockIdx.x - KSTEPS - B_) * 512 + t;
        const int R = u / 160, c16 = u - R * 160;
        const float* src = V + (size_t)R * NF_ + c16 * 16;
        float4 f0 = ((const float4*)src)[0];
        float4 f1 = ((const float4*)src)[1];
        float4 f2 = ((const float4*)src)[2];
        float4 f3 = ((const float4*)src)[3];
        int4 w;
        w.x = __builtin_amdgcn_cvt_pk_fp8_f32(f0.x, f0.y, 0, false);
        w.x = __builtin_amdgcn_cvt_pk_fp8_f32(f0.z, f0.w, w.x, true);
        w.y = __builtin_amdgcn_cvt_pk_fp8_f32(f1.x, f1.y, 0, false);
        w.y = __builtin_amdgcn_cvt_pk_fp8_f32(f1.z, f1.w, w.y, true);
        w.z = __builtin_amdgcn_cvt_pk_fp8_f32(f2.x, f2.y, 0, false);
        w.z = __builtin_amdgcn_cvt_pk_fp8_f32(f2.z, f2.w, w.z, true);
        w.w = __builtin_amdgcn_cvt_pk_fp8_f32(f3.x, f3.y, 0, false);
        w.w = __builtin_amdgcn_cvt_pk_fp8_f32(f3.z, f3.w, w.w, true);
        const int mtile = R / BM, row = R - mtile * BM;     // row 0..125
        const int T = c16 >> 3, s = c16 & 7;
        *(int4*)(Aws + ((size_t)(mtile * NMACRO + T) << 14) + row * 128 + s * 16) = w;
    }
}

// ---------------- kernel 2: slim fp8 MX-scale MFMA GEMM + fused Hon ----------------
// BM=126, grid 256 (1/CU), 8 waves 2Mx4N, wave 64x160, acc[4][10].
// A: fp8 gload_lds dbuf 2x16KB (source-side XOR swizzle); B: fp8 5-reg rolling window.
// 1 barrier + 1 counted vmcnt(10) per K128 macro. No conv, no fp32 in loop.
__global__ __launch_bounds__(512, 2)
void gemm_off(const unsigned char* __restrict__ Aws, const unsigned char* __restrict__ Bws,
              const float* __restrict__ b_off, const float* __restrict__ b_ovoff,
              const float* __restrict__ b_on, float* __restrict__ HSoff,
              float* __restrict__ Hon) {
    __shared__ alignas(16) unsigned char Afp8[2][ATILE];   // 2 x 16 KB
    __shared__ float HonLds[2][O2_];

    const int tid  = threadIdx.x;
    const int mt   = blockIdx.x;
    const int lane = tid & 63;
    const int wv   = tid >> 6;
    const int wm   = wv >> 2, wn = wv & 3;     // 2M x 4N, wave tile 64x160
    const int wvu  = __builtin_amdgcn_readfirstlane(wv);

    // stage source offsets (tile-local, inverse-XOR of the AFLD swizzle)
    // chunk c0 = tid (rows 0..63), c1 = 512+tid (rows 64..127, src clamped to 125)
    const int row0 = tid >> 3, seg = tid & 7;
    const int row1 = 64 + row0, rowc1 = row1 > 125 ? 125 : row1;
    const unsigned off0 = (unsigned)(row0 * 128 + (((seg >> 1) ^ (row0 & 3)) << 5) + (seg & 1) * 16);
    const unsigned off1 = (unsigned)(rowc1 * 128 + (((seg >> 1) ^ (rowc1 & 3)) << 5) + (seg & 1) * 16);
    const unsigned char* atile0 = Aws + (size_t)mt * NMACRO * ATILE;

    // B frag base (R14-validated layout)
    const unsigned char* bbase = Bws + ((size_t)(wn * 160 + (lane & 15))) * 128 + (lane >> 4) * 32;
#define BLD(T_, nf_) (*(const v8i*)(bbase + (size_t)(T_) * MAC_BYTES + (nf_) * 2048))

    // A frag: row = wm*64 + mf*16 + (lane&15); addr = row*128 + ((q ^ (row&3))<<5), q = lane>>4
    const unsigned abase = (unsigned)(wm * 64 * 128 + (lane & 15) * 128 +
                                      (((lane >> 4) ^ (lane & 3)) << 5));
#define AFLD(dst_, buf_, mf_) dst_ = *(const v8i*)&Afp8[buf_][abase + (mf_) * 2048];

    f32x4 acc[4][10];
#pragma unroll
    for (int mf = 0; mf < 4; ++mf)
#pragma unroll
        for (int nf = 0; nf < 10; ++nf)
            acc[mf][nf] = (f32x4){0.f, 0.f, 0.f, 0.f};

    auto stage = [&](int buf, int T) {
        const unsigned char* tp = atile0 + (size_t)T * ATILE;
        __builtin_amdgcn_global_load_lds(
            (const __attribute__((address_space(1))) void*)(tp + off0),
            (__attribute__((address_space(3))) void*)(&Afp8[buf][wvu * 1024]), 16, 0, 0);
        __builtin_amdgcn_global_load_lds(
            (const __attribute__((address_space(1))) void*)(tp + off1),
            (__attribute__((address_space(3))) void*)(&Afp8[buf][8192 + wvu * 1024]), 16, 0, 0);
    };

#define MFMA1(abf_, bq_, mf_, nf_) \
    acc[mf_][nf_] = __builtin_amdgcn_mfma_scale_f32_16x16x128_f8f6f4( \
        abf_, bq_, acc[mf_][nf_], 0, 0, 0, SCA, 0, SCB);

#define C4(bv_, nf_) { \
    __builtin_amdgcn_s_setprio(1); \
    MFMA1(af0, bv_, 0, nf_); MFMA1(af1, bv_, 1, nf_); \
    MFMA1(af2, bv_, 2, nf_); MFMA1(af3, bv_, 3, nf_); \
    __builtin_amdgcn_s_setprio(0); }

    v8i b0, b1, b2, b3, b4, af0, af1, af2, af3;

    // ---- prologue ----
    stage(0, 0);                                              // 2 vm
    b0 = BLD(0, 0); b1 = BLD(0, 1); b2 = BLD(0, 2); b3 = BLD(0, 3); b4 = BLD(0, 4);  // 5 vm
    asm volatile("s_waitcnt vmcnt(5)" ::: "memory");          // retire stage(0)
    __builtin_amdgcn_sched_barrier(0);
    __builtin_amdgcn_s_barrier();
    __builtin_amdgcn_sched_barrier(0);

    int cur = 0;
    for (int T = 0; T < NMACRO; ++T) {
        // A frags for this macro
        AFLD(af0, cur, 0); AFLD(af1, cur, 1); AFLD(af2, cur, 2); AFLD(af3, cur, 3);
        asm volatile("s_waitcnt lgkmcnt(0)" ::: "memory");
        __builtin_amdgcn_sched_barrier(0);

        // stage next macro (clamped dummy at T=19; never read)
        stage(cur ^ 1, T + 1 < NMACRO ? T + 1 : NMACRO - 1);

        // 10 nf clusters; B window reload-after-use (period 10, window 5)
        C4(b0, 0); b0 = BLD(T, 5);
        C4(b1, 1); b1 = BLD(T, 6);
        C4(b2, 2); b2 = BLD(T, 7);
        C4(b3, 3); b3 = BLD(T, 8);
        C4(b4, 4); b4 = BLD(T, 9);
        C4(b0, 5); b0 = BLD(T + 1, 0);     // T=19 reads pad macro 20 (allocated)
        C4(b1, 6); b1 = BLD(T + 1, 1);
        C4(b2, 7); b2 = BLD(T + 1, 2);
        C4(b3, 8); b3 = BLD(T + 1, 3);
        C4(b4, 9); b4 = BLD(T + 1, 4);

        asm volatile("s_waitcnt vmcnt(10)" ::: "memory");     // retire stage; keep 10 BLDs flying
        __builtin_amdgcn_sched_barrier(0);
        __builtin_amdgcn_s_barrier();
        __builtin_amdgcn_sched_barrier(0);
        cur ^= 1;
    }

    // ---- epilogue: off-site -> HSoff (+bias); on-site -> block mean -> Hon ----
    if (tid < 2 * O2_) HonLds[tid / O2_][tid % O2_] = 0.f;
    __syncthreads();

    const int c16 = lane & 15, rg = lane >> 4;
#pragma unroll
    for (int nf = 0; nf < 10; ++nf) {
        const int C = wn * 160 + nf * 16 + c16;
        if (C >= NSTORE) continue;
        const float bias = (C < O2_) ? b_off[C] : b_ovoff[C - O2_];
#pragma unroll
        for (int mf = 0; mf < 4; ++mf) {
            const int L = wm * 64 + mf * 16 + rg * 4;
#pragma unroll
            for (int jj = 0; jj < 4; ++jj) {
                const int row = L + jj;
                if (row < BM)
                    HSoff[(size_t)(mt * BM + row) * CSTRIDE + C] = acc[mf][nf][jj] + bias;
            }
        }
    }
#pragma unroll
    for (int nf = 0; nf < 10; ++nf) {
        const int C = wn * 160 + nf * 16 + c16;
        if (C < NSTORE || C >= NCOLS) continue;
        const int cc = C - NSTORE;
        float s0 = 0.f, s1 = 0.f;
#pragma unroll
        for (int mf = 0; mf < 4; ++mf) {
            const int L = wm * 64 + mf * 16 + rg * 4;
#pragma unroll
            for (int jj = 0; jj < 4; ++jj) {
                const int row = L + jj;
                const float v = acc[mf][nf][jj];
                if (row < NPAIR)       s0 += v;
                else if (row < BM)     s1 += v;
            }
        }
        s0 += __shfl_down(s0, 32); s0 += __shfl_down(s0, 16);
        s1 += __shfl_down(s1, 32); s1 += __shfl_down(s1, 16);
        if (lane < 16) {
            atomicAdd(&HonLds[0][cc], s0);
            atomicAdd(&HonLds[1][cc], s1);
        }
    }
    __syncthreads();
    if (tid < 2 * O2_) {
        const int atom = tid / O2_, c = tid % O2_;
        Hon[(size_t)(mt * 2 + atom) * O2_ + c] =
            HonLds[atom][c] * (1.f / (float)NPAIR) + b_on[c];
    }
#undef BLD
#undef AFLD
#undef MFMA1
#undef C4
}

// ---------------- kernel 3: assemble H and S, LDS-staged, fully coalesced ----------------
__global__ __launch_bounds__(256)
void assemble_k(const float* __restrict__ HSoff, const float* __restrict__ Hon,
                const int* __restrict__ Z, const float* __restrict__ ov_emb,
                const float* __restrict__ orbE, const float* __restrict__ s0E,
                float* __restrict__ H, float* __restrict__ S) {
    __shared__ float Ai[NPAIR * 197];
    __shared__ float Bj[2][16 * 200];
    __shared__ float Dg[O2_];
    __shared__ float Dd[NORB_];

    const int bid = blockIdx.x;
    const int h = bid & 1, i = (bid >> 1) & 63, b = bid >> 7;
    const int t = threadIdx.x;
    const int g = b * A_ + i;
    const int z = Z[g];
    float* out = (h ? S : H) + (size_t)b * AO_ * AO_;

    const float* abase = HSoff + (size_t)g * NPAIR * CSTRIDE + h * O2_;
    for (int u = t; u < NPAIR * O2_; u += 256) {
        int jj = u / O2_, e = u - jj * O2_;
        Ai[jj * 197 + e] = abase[(size_t)jj * CSTRIDE + e];
    }
    if (t < O2_)   Dg[t] = h ? ov_emb[(size_t)z * O2_ + t]   : Hon[(size_t)g * O2_ + t];
    if (t < NORB_) Dd[t] = h ? s0E[(size_t)z * NORB_ + t]    : orbE[(size_t)z * NORB_ + t];

    auto stageB = [&](int buf, int jc) {
        for (int u = t; u < 16 * O2_; u += 256) {
            int jl = u / O2_, e = u - jl * O2_;
            int j = jc * 16 + jl;
            if (j != i) {
                int idx = (i < j) ? i : i - 1;
                Bj[buf][jl * 200 + e] =
                    HSoff[((size_t)(b * A_ + j) * NPAIR + idx) * CSTRIDE + h * O2_ + e];
            }
        }
    };
    stageB(0, 0);
    __syncthreads();

    const int tj = t / NORB_, tq = t - tj * NORB_;
    for (int jc = 0; jc < 4; ++jc) {
        if (jc < 3) stageB((jc + 1) & 1, jc + 1);
        if (t < 224) {
            const int j = jc * 16 + tj;
            const int cur = jc & 1;
#pragma unroll
            for (int p = 0; p < NORB_; ++p) {
                float v;
                if (j == i) {
                    v = 0.5f * (Dg[p * NORB_ + tq] + Dg[tq * NORB_ + p]);
                    if (p == tq) v += Dd[p];
                } else {
                    int jj = (j < i) ? j : j - 1;
                    v = 0.5f * (Ai[jj * 197 + p * NORB_ + tq] + Bj[cur][tj * 200 + tq * NORB_ + p]);
                }
                out[(size_t)(i * NORB_ + p) * AO_ + jc * 224 + t] = v;
            }
        }
        __syncthreads();
    }
}

// ---------------- launcher ----------------
extern "C" void kernel_launch(void* const* d_in, const int* in_sizes, int n_in,
                              void* d_out, int out_size, void* d_ws, size_t ws_size,
                              hipStream_t stream) {
    const int*   Z       = (const int*)  d_in[0];
    const float* x       = (const float*)d_in[2];
    const float* V       = (const float*)d_in[3];
    const float* W_off   = (const float*)d_in[4];
    const float* b_off   = (const float*)d_in[5];
    const float* W_on    = (const float*)d_in[6];
    const float* b_on    = (const float*)d_in[7];
    const float* W_ovoff = (const float*)d_in[8];
    const float* b_ovoff = (const float*)d_in[9];
    const float* ov_emb  = (const float*)d_in[10];
    const float* orbE    = (const float*)d_in[11];
    const float* s0E     = (const float*)d_in[12];
    const float* W1      = (const float*)d_in[13];
    const float* b1      = (const float*)d_in[14];
    const float* W2      = (const float*)d_in[15];
    const float* b2      = (const float*)d_in[16];

    float* H = (float*)d_out;
    float* S = H + (size_t)B_ * AO_ * AO_;
    float* E = S + (size_t)B_ * AO_ * AO_;

    char* ws = (char*)d_ws;
    unsigned char* Bws = (unsigned char*)ws;                        // 21 x 81920 (macro 20 = pad)
    unsigned char* Aws = (unsigned char*)(ws + (size_t)4 * 1024 * 1024);   // 256*20*16384 = 80 MB
    float* HSoff = (float*)(ws + (size_t)88  * 1024 * 1024);        // 51,609,600 B
    float* Hon   = (float*)(ws + (size_t)142 * 1024 * 1024);        //    401,408 B

    const int conv_blocks = (32256 * 160) / 512;                    // 10080
    prep_all  <<<KSTEPS + B_ + conv_blocks, 512, 0, stream>>>(
        W_off, W_ovoff, W_on, Bws, x, W1, b1, W2, b2, E, V, Aws);
    gemm_off  <<<256,  512, 0, stream>>>(Aws, Bws, b_off, b_ovoff, b_on, HSoff, Hon);
    assemble_k<<<1024, 256, 0, stream>>>(HSoff, Hon, Z, ov_emb, orbE, s0E, H, S);
}

// Round 16
// 267.481 us; speedup vs baseline: 2.1452x; 1.0143x over previous
//
#include <hip/hip_runtime.h>

// ---------------- problem constants ----------------
#define B_      8
#define A_      64
#define NPAIR   63
#define NC_     128
#define NF_     2560    // K
#define O2_     196     // 14*14
#define NORB_   14
#define AO_     896
#define NCOLS   588     // computed cols: [H_off 196 | S_off 196 | H_on 196]
#define NSTORE  392     // cols stored to HSoff
#define CSTRIDE 400     // padded col stride of HSoff
#define KSTEPS  80      // K32 slices
#define NMACRO  20      // K128 macro-steps
#define BM      126     // 2 atoms x 63 pair-rows per block
#define BN      640
#define MAC_BYTES 81920 // B: 640 cols x 128 k-bytes per macro

typedef float f32x4 __attribute__((ext_vector_type(4)));
typedef int   v8i   __attribute__((ext_vector_type(8)));

#define SCA 0x7F7F7F7F   // A scale: e8m0 127 = 1.0 (validated R14/R15)
#define SCB 0x7C7C7C7C   // B scale: e8m0 124 = 2^-3 (W packed x8, validated R14/R15)

// ---------------- kernel 1: fused {pack W -> fp8 | energy head} ----------------
__global__ __launch_bounds__(512)
void prep_energy(const float* __restrict__ W_off, const float* __restrict__ W_ovoff,
                 const float* __restrict__ W_on, unsigned char* __restrict__ Bws,
                 const float* __restrict__ x, const float* __restrict__ W1,
                 const float* __restrict__ b1, const float* __restrict__ W2,
                 const float* __restrict__ b2, float* __restrict__ E) {
    const int t = threadIdx.x;
    if (blockIdx.x < KSTEPS) {
        __shared__ float wt[32 * BN];
        const int ks = blockIdx.x;
        for (int e = t; e < 32 * BN; e += 512) {
            int kl = e / BN, c = e - kl * BN;
            int kg = ks * 32 + kl;
            float v = 0.f;
            if (c < O2_)          v = W_off  [(size_t)kg * O2_ + c];
            else if (c < 2 * O2_) v = W_ovoff[(size_t)kg * O2_ + (c - O2_)];
            else if (c < 3 * O2_) v = W_on   [(size_t)kg * O2_ + (c - 2 * O2_)];
            wt[kl * BN + c] = v * 8.0f;
        }
        __syncthreads();
        unsigned char* out = Bws + (size_t)(ks >> 2) * MAC_BYTES + (ks & 3) * 32;
        for (int u = t; u < BN * 8; u += 512) {
            int n = u >> 3, q = u & 7;
            int w = __builtin_amdgcn_cvt_pk_fp8_f32(wt[(q*4+0)*BN+n], wt[(q*4+1)*BN+n], 0, false);
            w     = __builtin_amdgcn_cvt_pk_fp8_f32(wt[(q*4+2)*BN+n], wt[(q*4+3)*BN+n], w, true);
            *(int*)(out + (size_t)n * 128 + q * 4) = w;
        }
    } else {
        __shared__ float partial[8];
        const int b = blockIdx.x - KSTEPS;
        const int lane = t & 63;
        const int w = t >> 6;
        float esum = 0.f;
        for (int aa = 0; aa < 8; ++aa) {
            const int a = w * 8 + aa;
            const float* xr = x + (size_t)(b * A_ + a) * NC_;
            float hj = b1[lane];
            for (int k = 0; k < NC_; ++k) hj = fmaf(xr[k], W1[k * 64 + lane], hj);
            float sp = fmaxf(hj, 0.f) + log1pf(expf(-fabsf(hj))) - 0.69314718055994531f;
            float v = sp * W2[lane];
            for (int off = 32; off; off >>= 1) v += __shfl_down(v, off);
            if (lane == 0) esum += v + b2[0];
        }
        if (lane == 0) partial[w] = esum;
        __syncthreads();
        if (t == 0) {
            float e = 0.f;
            for (int k = 0; k < 8; ++k) e += partial[k];
            E[b] = e;
        }
    }
}

// ---------------- kernel 2: fused fp8 GEMM reading fp32 V directly ----------------
// BM=126, 256 blocks (1/CU), 8 waves 2Mx4N, wave 64x160, acc[4][10].
// Per K128 macro: stage T+1 (fp32 ring, 8 gload_lds at top) -> 40 MFMA + 10 B reloads
// -> vmcnt(10) -> conv T+1 (own-chunk back-read, cvt_pk, swizzled fp8 write) -> barrier.
__global__ __launch_bounds__(512, 2)
void gemm_off(const float* __restrict__ V, const unsigned char* __restrict__ Bws,
              const float* __restrict__ b_off, const float* __restrict__ b_ovoff,
              const float* __restrict__ b_on, float* __restrict__ HSoff,
              float* __restrict__ Hon) {
    __shared__ alignas(16) float Ring[4 * 4096];              // 64 KB: 4 K32 slices fp32
    __shared__ alignas(16) unsigned char Afp8[2][16384];      // 32 KB fp8 dbuf
    __shared__ float HonLds[2][O2_];

    const int tid  = threadIdx.x;
    const int mt   = blockIdx.x;
    const int lane = tid & 63;
    const int wv   = tid >> 6;
    const int wm   = wv >> 2, wn = wv & 3;     // 2M x 4N, wave tile 64x160
    const int wvu  = __builtin_amdgcn_readfirstlane(wv);

    // stage map: thread covers rows (tid>>3) and 64+(tid>>3) (clamped), k-seg tid&7
    const int srow0 = tid >> 3;
    const int srow1 = 64 + srow0 > 125 ? 125 : 64 + srow0;
    const float* src0 = V + (size_t)(mt * BM + srow0) * NF_ + (tid & 7) * 4;
    const float* src1 = V + (size_t)(mt * BM + srow1) * NF_ + (tid & 7) * 4;

    // B frag base (validated layout)
    const unsigned char* bbase = Bws + ((size_t)(wn * 160 + (lane & 15))) * 128 + (lane >> 4) * 32;
#define BLD(T_, nf_) (*(const v8i*)(bbase + (size_t)(T_) * MAC_BYTES + (nf_) * 2048))

    // A frag: row = wm*64 + mf*16 + (lane&15); addr = row*128 + ((q ^ (row&3))<<5)
    const unsigned abase = (unsigned)(wm * 8192 + (lane & 15) * 128 +
                                      (((lane >> 4) ^ (lane & 3)) << 5));
#define AFLD(dst_, buf_, mf_) dst_ = *(const v8i*)&Afp8[buf_][abase + (mf_) * 2048];

    f32x4 acc[4][10];
#pragma unroll
    for (int mf = 0; mf < 4; ++mf)
#pragma unroll
        for (int nf = 0; nf < 10; ++nf)
            acc[mf][nf] = (f32x4){0.f, 0.f, 0.f, 0.f};

    auto stage = [&](int T1) {     // stage all 4 K32 slices of macro T1 into Ring
#pragma unroll
        for (int s = 0; s < 4; ++s) {
            const int k32 = T1 * 4 + s;
            __builtin_amdgcn_global_load_lds(
                (const __attribute__((address_space(1))) void*)(src0 + (size_t)k32 * 32),
                (__attribute__((address_space(3))) void*)(&Ring[s * 4096 + wvu * 256]), 16, 0, 0);
            __builtin_amdgcn_global_load_lds(
                (const __attribute__((address_space(1))) void*)(src1 + (size_t)k32 * 32),
                (__attribute__((address_space(3))) void*)(&Ring[s * 4096 + 2048 + wvu * 256]), 16, 0, 0);
        }
    };
    // conv: thread back-reads exactly its own staged 16B chunks (lane-contiguous, conflict-free),
    // writes 4 fp8 bytes per (round, slice) at the AFLD swizzle position (2-way write, free).
    auto conv = [&](int dstbuf) {
#pragma unroll
        for (int r = 0; r < 2; ++r) {
            const int row = r * 64 + (tid >> 3);
            const unsigned wrbase = (unsigned)(row * 128) ;
            const unsigned rsw = (unsigned)(row & 3);
#pragma unroll
            for (int s = 0; s < 4; ++s) {
                float4 f = *(const float4*)&Ring[s * 4096 + r * 2048 + tid * 4];
                int w = __builtin_amdgcn_cvt_pk_fp8_f32(f.x, f.y, 0, false);
                w     = __builtin_amdgcn_cvt_pk_fp8_f32(f.z, f.w, w, true);
                *(int*)&Afp8[dstbuf][wrbase + (((unsigned)s ^ rsw) << 5) + (tid & 7) * 4] = w;
            }
        }
    };

#define MFMA1(abf_, bq_, mf_, nf_) \
    acc[mf_][nf_] = __builtin_amdgcn_mfma_scale_f32_16x16x128_f8f6f4( \
        abf_, bq_, acc[mf_][nf_], 0, 0, 0, SCA, 0, SCB);

#define C4(bv_, nf_) { \
    __builtin_amdgcn_s_setprio(1); \
    MFMA1(af0, bv_, 0, nf_); MFMA1(af1, bv_, 1, nf_); \
    MFMA1(af2, bv_, 2, nf_); MFMA1(af3, bv_, 3, nf_); \
    __builtin_amdgcn_s_setprio(0); }

    v8i b0, b1, b2, b3, b4, af0, af1, af2, af3;

    // ---- prologue: stage macro 0; B window; conv macro 0 -> buf 0 ----
    stage(0);                                                 // 8 vm
    b0 = BLD(0, 0); b1 = BLD(0, 1); b2 = BLD(0, 2); b3 = BLD(0, 3); b4 = BLD(0, 4);  // 5 vm
    asm volatile("s_waitcnt vmcnt(5)" ::: "memory");          // retire the 8 stages
    __builtin_amdgcn_sched_barrier(0);
    conv(0);
    asm volatile("s_waitcnt lgkmcnt(0)" ::: "memory");
    __builtin_amdgcn_s_barrier();
    __builtin_amdgcn_sched_barrier(0);

    int cur = 0;
    for (int T = 0; T < NMACRO; ++T) {
        // A frags for macro T (compiler tracks ds deps into MFMA)
        AFLD(af0, cur, 0); AFLD(af1, cur, 1); AFLD(af2, cur, 2); AFLD(af3, cur, 3);

        // stage macro T+1 at top (newest in FIFO; prev-macro B-loads are older, so
        // B-use waits never retire-chain these stages)
        if (T < NMACRO - 1) stage(T + 1);

        // 10 nf clusters; B window reload-after-use (period 10, window 5)
        C4(b0, 0); b0 = BLD(T, 5);
        C4(b1, 1); b1 = BLD(T, 6);
        C4(b2, 2); b2 = BLD(T, 7);
        C4(b3, 3); b3 = BLD(T, 8);
        C4(b4, 4); b4 = BLD(T, 9);
        C4(b0, 5); b0 = BLD(T + 1, 0);     // T=19 reads pad macro 20 (allocated)
        C4(b1, 6); b1 = BLD(T + 1, 1);
        C4(b2, 7); b2 = BLD(T + 1, 2);
        C4(b3, 8); b3 = BLD(T + 1, 3);
        C4(b4, 9); b4 = BLD(T + 1, 4);

        if (T < NMACRO - 1) {
            asm volatile("s_waitcnt vmcnt(10)" ::: "memory"); // retire 8 stages; keep 10 BLDs
            __builtin_amdgcn_sched_barrier(0);
            conv(cur ^ 1);                                    // macro T+1 -> other fp8 buf
        }
        asm volatile("s_waitcnt lgkmcnt(0)" ::: "memory");
        __builtin_amdgcn_sched_barrier(0);
        __builtin_amdgcn_s_barrier();
        __builtin_amdgcn_sched_barrier(0);
        cur ^= 1;
    }

    // ---- epilogue: off-site -> HSoff (+bias); on-site -> block mean -> Hon ----
    if (tid < 2 * O2_) HonLds[tid / O2_][tid % O2_] = 0.f;
    __syncthreads();

    const int c16 = lane & 15, rg = lane >> 4;
#pragma unroll
    for (int nf = 0; nf < 10; ++nf) {
        const int C = wn * 160 + nf * 16 + c16;
        if (C >= NSTORE) continue;
        const float bias = (C < O2_) ? b_off[C] : b_ovoff[C - O2_];
#pragma unroll
        for (int mf = 0; mf < 4; ++mf) {
            const int L = wm * 64 + mf * 16 + rg * 4;
#pragma unroll
            for (int jj = 0; jj < 4; ++jj) {
                const int row = L + jj;
                if (row < BM)
                    HSoff[(size_t)(mt * BM + row) * CSTRIDE + C] = acc[mf][nf][jj] + bias;
            }
        }
    }
#pragma unroll
    for (int nf = 0; nf < 10; ++nf) {
        const int C = wn * 160 + nf * 16 + c16;
        if (C < NSTORE || C >= NCOLS) continue;
        const int cc = C - NSTORE;
        float s0 = 0.f, s1 = 0.f;
#pragma unroll
        for (int mf = 0; mf < 4; ++mf) {
            const int L = wm * 64 + mf * 16 + rg * 4;
#pragma unroll
            for (int jj = 0; jj < 4; ++jj) {
                const int row = L + jj;
                const float v = acc[mf][nf][jj];
                if (row < NPAIR)       s0 += v;
                else if (row < BM)     s1 += v;
            }
        }
        s0 += __shfl_down(s0, 32); s0 += __shfl_down(s0, 16);
        s1 += __shfl_down(s1, 32); s1 += __shfl_down(s1, 16);
        if (lane < 16) {
            atomicAdd(&HonLds[0][cc], s0);
            atomicAdd(&HonLds[1][cc], s1);
        }
    }
    __syncthreads();
    if (tid < 2 * O2_) {
        const int atom = tid / O2_, c = tid % O2_;
        Hon[(size_t)(mt * 2 + atom) * O2_ + c] =
            HonLds[atom][c] * (1.f / (float)NPAIR) + b_on[c];
    }
#undef BLD
#undef AFLD
#undef MFMA1
#undef C4
}

// ---------------- kernel 3: assemble H and S, LDS-staged, fully coalesced ----------------
__global__ __launch_bounds__(256)
void assemble_k(const float* __restrict__ HSoff, const float* __restrict__ Hon,
                const int* __restrict__ Z, const float* __restrict__ ov_emb,
                const float* __restrict__ orbE, const float* __restrict__ s0E,
                float* __restrict__ H, float* __restrict__ S) {
    __shared__ float Ai[NPAIR * 197];
    __shared__ float Bj[2][16 * 200];
    __shared__ float Dg[O2_];
    __shared__ float Dd[NORB_];

    const int bid = blockIdx.x;
    const int h = bid & 1, i = (bid >> 1) & 63, b = bid >> 7;
    const int t = threadIdx.x;
    const int g = b * A_ + i;
    const int z = Z[g];
    float* out = (h ? S : H) + (size_t)b * AO_ * AO_;

    const float* abase = HSoff + (size_t)g * NPAIR * CSTRIDE + h * O2_;
    for (int u = t; u < NPAIR * O2_; u += 256) {
        int jj = u / O2_, e = u - jj * O2_;
        Ai[jj * 197 + e] = abase[(size_t)jj * CSTRIDE + e];
    }
    if (t < O2_)   Dg[t] = h ? ov_emb[(size_t)z * O2_ + t]   : Hon[(size_t)g * O2_ + t];
    if (t < NORB_) Dd[t] = h ? s0E[(size_t)z * NORB_ + t]    : orbE[(size_t)z * NORB_ + t];

    auto stageB = [&](int buf, int jc) {
        for (int u = t; u < 16 * O2_; u += 256) {
            int jl = u / O2_, e = u - jl * O2_;
            int j = jc * 16 + jl;
            if (j != i) {
                int idx = (i < j) ? i : i - 1;
                Bj[buf][jl * 200 + e] =
                    HSoff[((size_t)(b * A_ + j) * NPAIR + idx) * CSTRIDE + h * O2_ + e];
            }
        }
    };
    stageB(0, 0);
    __syncthreads();

    const int tj = t / NORB_, tq = t - tj * NORB_;
    for (int jc = 0; jc < 4; ++jc) {
        if (jc < 3) stageB((jc + 1) & 1, jc + 1);
        if (t < 224) {
            const int j = jc * 16 + tj;
            const int cur = jc & 1;
#pragma unroll
            for (int p = 0; p < NORB_; ++p) {
                float v;
                if (j == i) {
                    v = 0.5f * (Dg[p * NORB_ + tq] + Dg[tq * NORB_ + p]);
                    if (p == tq) v += Dd[p];
                } else {
                    int jj = (j < i) ? j : j - 1;
                    v = 0.5f * (Ai[jj * 197 + p * NORB_ + tq] + Bj[cur][tj * 200 + tq * NORB_ + p]);
                }
                out[(size_t)(i * NORB_ + p) * AO_ + jc * 224 + t] = v;
            }
        }
        __syncthreads();
    }
}

// ---------------- launcher ----------------
extern "C" void kernel_launch(void* const* d_in, const int* in_sizes, int n_in,
                              void* d_out, int out_size, void* d_ws, size_t ws_size,
                              hipStream_t stream) {
    const int*   Z       = (const int*)  d_in[0];
    const float* x       = (const float*)d_in[2];
    const float* V       = (const float*)d_in[3];
    const float* W_off   = (const float*)d_in[4];
    const float* b_off   = (const float*)d_in[5];
    const float* W_on    = (const float*)d_in[6];
    const float* b_on    = (const float*)d_in[7];
    const float* W_ovoff = (const float*)d_in[8];
    const float* b_ovoff = (const float*)d_in[9];
    const float* ov_emb  = (const float*)d_in[10];
    const float* orbE    = (const float*)d_in[11];
    const float* s0E     = (const float*)d_in[12];
    const float* W1      = (const float*)d_in[13];
    const float* b1      = (const float*)d_in[14];
    const float* W2      = (const float*)d_in[15];
    const float* b2      = (const float*)d_in[16];

    float* H = (float*)d_out;
    float* S = H + (size_t)B_ * AO_ * AO_;
    float* E = S + (size_t)B_ * AO_ * AO_;

    char* ws = (char*)d_ws;
    unsigned char* Bws = (unsigned char*)ws;                        // 21 x 81920 (macro 20 = pad)
    float* HSoff = (float*)(ws + (size_t)4  * 1024 * 1024);         // 51,609,600 B
    float* Hon   = (float*)(ws + (size_t)60 * 1024 * 1024);         //    401,408 B

    prep_energy<<<KSTEPS + B_, 512, 0, stream>>>(W_off, W_ovoff, W_on, Bws,
                                                 x, W1, b1, W2, b2, E);
    gemm_off   <<<256,  512, 0, stream>>>(V, Bws, b_off, b_ovoff, b_on, HSoff, Hon);
    assemble_k <<<1024, 256, 0, stream>>>(HSoff, Hon, Z, ov_emb, orbE, s0E, H, S);
}